// Round 10
// baseline (566.226 us; speedup 1.0000x reference)
//
#include <hip/hip_runtime.h>

#define NUSER 100000
#define NITEM 100000
#define NEDGE 1600000
#define HID 64
#define NPB 256                 // nodes per bucket (pow2: bucket = dst>>8)
#define NBKT 391                // ceil(100000/256)
#define BCAP 5120               // fixed bucket capacity (mean 4096, sigma~64)
#define ACHUNK 8192             // partition chunk (edges)
#define NCHUNK ((NEDGE + ACHUNK - 1) / ACHUNK)   // 196 per edge type

typedef float f32x4 __attribute__((ext_vector_type(4)));

__device__ __forceinline__ unsigned short f2bf(float x) {
  unsigned int u; __builtin_memcpy(&u, &x, 4);
  u += 0x7fffu + ((u >> 16) & 1u);
  return (unsigned short)(u >> 16);
}
__device__ __forceinline__ float bflo(unsigned int u) {
  unsigned int v = u << 16; float f; __builtin_memcpy(&f, &v, 4); return f;
}
__device__ __forceinline__ float bfhi(unsigned int u) {
  unsigned int v = u & 0xffff0000u; float f; __builtin_memcpy(&f, &v, 4); return f;
}

// ---------------------------------------------------------------------------
// Dispatch 1: partition (CSR pass 1) || input linears, role-split grid.
// partition role: bucket edges into fixed-capacity regions [b*BCAP, ...);
// gemm role: C[M,64] = relu(A[M,K] @ W[K,64] + bias), K in {128, 64}.
// ---------------------------------------------------------------------------
__global__ __launch_bounds__(256) void fused_a(
    // partition args
    const int* __restrict__ srcA, const int* __restrict__ dstA, int* curA, unsigned int* pairsA,
    const int* __restrict__ srcB, const int* __restrict__ dstB, int* curB, unsigned int* pairsB,
    int E,
    // gemm_in2 args
    const float* __restrict__ A0, const float* __restrict__ W0,
    const float* __restrict__ bias0, float* __restrict__ C0,
    const float* __restrict__ A1, const float* __restrict__ W1,
    const float* __restrict__ bias1, float* __restrict__ C1, int M,
    int part_blocks)
{
  __shared__ union {
    struct { float Ws[128 * 64]; float As[64 * 68]; } g;
    struct { int h[NBKT]; int c[NBKT]; } p;
  } sm;
  const int tid = threadIdx.x;

  if ((int)blockIdx.x < part_blocks) {
    // ---- partition role ----
    const int half = part_blocks >> 1;   // chunks per type
    const bool isB = (int)blockIdx.x >= half;
    const int chunk = isB ? blockIdx.x - half : blockIdx.x;
    const int* src = isB ? srcB : srcA;
    const int* dst = isB ? dstB : dstA;
    int* cur = isB ? curB : curA;
    unsigned int* pairs = isB ? pairsB : pairsA;
    const int e0 = chunk * ACHUNK;
    const int e1 = min(e0 + ACHUNK, E);
    for (int i = tid; i < NBKT; i += 256) sm.p.h[i] = 0;
    __syncthreads();
    for (int e = e0 + tid; e < e1; e += 256)
      atomicAdd(&sm.p.h[__builtin_nontemporal_load(dst + e) >> 8], 1);
    __syncthreads();
    for (int i = tid; i < NBKT; i += 256) {
      int v = sm.p.h[i];
      if (v) sm.p.c[i] = i * BCAP + atomicAdd(&cur[i], v);
    }
    __syncthreads();
    for (int e = e0 + tid; e < e1; e += 256) {
      int d = __builtin_nontemporal_load(dst + e);
      int s = __builtin_nontemporal_load(src + e);
      int b = d >> 8;
      int p = atomicAdd(&sm.p.c[b], 1);
      pairs[p] = ((unsigned int)(d & 255) << 24) | (unsigned int)s;
    }
    return;
  }

  // ---- gemm_in2 role ----
  const int gb = blockIdx.x - part_blocks;
  const int side = gb & 1;
  const int t0 = gb >> 1;
  const int nb = (gridDim.x - part_blocks) >> 1;
  const float* A; const float* W; const float* bias; float* C; int K;
  if (side == 0) { A = A0; W = W0; bias = bias0; C = C0; K = 128; }
  else           { A = A1; W = W1; bias = bias1; C = C1; K = 64; }

  for (int i = tid; i < K * 16; i += 256)
    ((float4*)sm.g.Ws)[i] = ((const float4*)W)[i];

  const int tx = tid & 15;
  const int ty = tid >> 4;
  float4 bv = ((const float4*)bias)[tx];

  const int ntiles = (M + 63) >> 6;
  for (int t = t0; t < ntiles; t += nb) {
    const int row0 = t << 6;
    float acc[4][4] = {};
    for (int kb = 0; kb < K; kb += 64) {
      __syncthreads();
      for (int i = tid; i < 1024; i += 256) {
        int r = i >> 4;
        int kk = (i & 15) << 2;
        int gr = row0 + r; if (gr > M - 1) gr = M - 1;
        *(float4*)&sm.g.As[r * 68 + kk] = *(const float4*)(A + (size_t)gr * K + kb + kk);
      }
      __syncthreads();
      #pragma unroll 8
      for (int k = 0; k < 64; ++k) {
        float4 w = *(const float4*)&sm.g.Ws[(kb + k) * 64 + tx * 4];
        float a0 = sm.g.As[(ty * 4 + 0) * 68 + k];
        float a1 = sm.g.As[(ty * 4 + 1) * 68 + k];
        float a2 = sm.g.As[(ty * 4 + 2) * 68 + k];
        float a3 = sm.g.As[(ty * 4 + 3) * 68 + k];
        acc[0][0] += a0 * w.x; acc[0][1] += a0 * w.y; acc[0][2] += a0 * w.z; acc[0][3] += a0 * w.w;
        acc[1][0] += a1 * w.x; acc[1][1] += a1 * w.y; acc[1][2] += a1 * w.z; acc[1][3] += a1 * w.w;
        acc[2][0] += a2 * w.x; acc[2][1] += a2 * w.y; acc[2][2] += a2 * w.z; acc[2][3] += a2 * w.w;
        acc[3][0] += a3 * w.x; acc[3][1] += a3 * w.y; acc[3][2] += a3 * w.z; acc[3][3] += a3 * w.w;
      }
    }
    #pragma unroll
    for (int r = 0; r < 4; ++r) {
      int gr = row0 + ty * 4 + r;
      if (gr < M) {
        float4 o = make_float4(fmaxf(acc[r][0] + bv.x, 0.f), fmaxf(acc[r][1] + bv.y, 0.f),
                               fmaxf(acc[r][2] + bv.z, 0.f), fmaxf(acc[r][3] + bv.w, 0.f));
        *(float4*)(C + (size_t)gr * 64 + tx * 4) = o;
      }
    }
  }
}

// ---------------------------------------------------------------------------
// Dispatch 2: bucket_fill (CSR pass 2) || dual GEMM layer 0, role-split grid.
// fill role: per-bucket degree hist -> scan -> int2 ptr -> scatter idx.
// dual role: Ga = bf16(A @ Wa); Tb = A @ Wb + bias (Tb may alias A row-wise).
// ---------------------------------------------------------------------------
__global__ __launch_bounds__(256) void fused_b(
    // bucket_fill args
    const unsigned int* __restrict__ pairsA, const int* __restrict__ cntA,
    int2* __restrict__ ptrA, int* __restrict__ idxA,
    const unsigned int* __restrict__ pairsB, const int* __restrict__ cntB,
    int2* __restrict__ ptrB, int* __restrict__ idxB, int n,
    // dual2 args
    const float* A0, const float* __restrict__ Wa0, const float* __restrict__ Wb0,
    const float* __restrict__ bias0, unsigned short* Ga0, float* Tb0,
    const float* A1, const float* __restrict__ Wa1, const float* __restrict__ Wb1,
    const float* __restrict__ bias1, unsigned short* Ga1, float* Tb1,
    int M, int fill_blocks)
{
  __shared__ union {
    struct { float Ws[64 * 128]; float As[64 * 68]; } g;
    struct { int h[NPB]; int cur[NPB]; } f;
  } sm;
  const int tid = threadIdx.x;

  if ((int)blockIdx.x < fill_blocks) {
    // ---- bucket_fill role ----
    const bool isB = (int)blockIdx.x >= NBKT;
    const int b = isB ? blockIdx.x - NBKT : blockIdx.x;
    const unsigned int* pairs = isB ? pairsB : pairsA;
    const int* cnt = isB ? cntB : cntA;
    int2* ptr = isB ? ptrB : ptrA;
    int* idx = isB ? idxB : idxA;
    const int ebase = b * BCAP;
    const int eend = ebase + min(cnt[b], BCAP);
    const int t = tid;
    sm.f.h[t] = 0;
    __syncthreads();
    for (int e = ebase + t; e < eend; e += 256)
      atomicAdd(&sm.f.h[pairs[e] >> 24], 1);
    __syncthreads();
    const int v = sm.f.h[t];
    __syncthreads();
    for (int off = 1; off < 256; off <<= 1) {
      int x = 0;
      if (t >= off) x = sm.f.h[t - off];
      __syncthreads();
      if (t >= off) sm.f.h[t] += x;
      __syncthreads();
    }
    const int excl = sm.f.h[t] - v;
    const int gnode = b * NPB + t;
    if (gnode < n) ptr[gnode] = make_int2(ebase + excl, ebase + excl + v);
    sm.f.cur[t] = excl;
    __syncthreads();
    for (int e = ebase + t; e < eend; e += 256) {
      unsigned int pk = pairs[e];
      int p = atomicAdd(&sm.f.cur[pk >> 24], 1);
      idx[ebase + p] = (int)(pk & 0xFFFFFFu);
    }
    return;
  }

  // ---- dual2 role ----
  const int gb = blockIdx.x - fill_blocks;
  const int half = (gridDim.x - fill_blocks) >> 1;
  const float* A; const float* Wa; const float* Wb; const float* bias;
  unsigned short* Ga; float* Tb; int t0;
  if (gb < half) {
    A = A0; Wa = Wa0; Wb = Wb0; bias = bias0; Ga = Ga0; Tb = Tb0; t0 = gb;
  } else {
    A = A1; Wa = Wa1; Wb = Wb1; bias = bias1; Ga = Ga1; Tb = Tb1; t0 = gb - half;
  }

  for (int i = tid; i < 2048; i += 256) {
    int k = i >> 5, cg = i & 31;
    float4 v = (cg < 16) ? ((const float4*)Wa)[k * 16 + cg]
                         : ((const float4*)Wb)[k * 16 + (cg - 16)];
    ((float4*)sm.g.Ws)[k * 32 + cg] = v;
  }

  const int tx = tid & 15;
  const int ty = tid >> 4;
  float4 bvB = ((const float4*)bias)[tx];

  const int ntiles = (M + 63) >> 6;
  for (int t = t0; t < ntiles; t += half) {
    const int row0 = t << 6;
    float accA[4][4] = {};
    float accB[4][4] = {};
    __syncthreads();
    for (int i = tid; i < 1024; i += 256) {
      int r = i >> 4;
      int kk = (i & 15) << 2;
      int gr = row0 + r; if (gr > M - 1) gr = M - 1;
      *(float4*)&sm.g.As[r * 68 + kk] = *(const float4*)(A + (size_t)gr * 64 + kk);
    }
    __syncthreads();
    #pragma unroll 8
    for (int k = 0; k < 64; ++k) {
      float4 wa = *(const float4*)&sm.g.Ws[k * 128 + tx * 4];
      float4 wb = *(const float4*)&sm.g.Ws[k * 128 + 64 + tx * 4];
      float a0 = sm.g.As[(ty * 4 + 0) * 68 + k];
      float a1 = sm.g.As[(ty * 4 + 1) * 68 + k];
      float a2 = sm.g.As[(ty * 4 + 2) * 68 + k];
      float a3 = sm.g.As[(ty * 4 + 3) * 68 + k];
      accA[0][0] += a0 * wa.x; accA[0][1] += a0 * wa.y; accA[0][2] += a0 * wa.z; accA[0][3] += a0 * wa.w;
      accA[1][0] += a1 * wa.x; accA[1][1] += a1 * wa.y; accA[1][2] += a1 * wa.z; accA[1][3] += a1 * wa.w;
      accA[2][0] += a2 * wa.x; accA[2][1] += a2 * wa.y; accA[2][2] += a2 * wa.z; accA[2][3] += a2 * wa.w;
      accA[3][0] += a3 * wa.x; accA[3][1] += a3 * wa.y; accA[3][2] += a3 * wa.z; accA[3][3] += a3 * wa.w;
      accB[0][0] += a0 * wb.x; accB[0][1] += a0 * wb.y; accB[0][2] += a0 * wb.z; accB[0][3] += a0 * wb.w;
      accB[1][0] += a1 * wb.x; accB[1][1] += a1 * wb.y; accB[1][2] += a1 * wb.z; accB[1][3] += a1 * wb.w;
      accB[2][0] += a2 * wb.x; accB[2][1] += a2 * wb.y; accB[2][2] += a2 * wb.z; accB[2][3] += a2 * wb.w;
      accB[3][0] += a3 * wb.x; accB[3][1] += a3 * wb.y; accB[3][2] += a3 * wb.z; accB[3][3] += a3 * wb.w;
    }
    #pragma unroll
    for (int r = 0; r < 4; ++r) {
      int gr = row0 + ty * 4 + r;
      if (gr < M) {
        ushort4 g;
        g.x = f2bf(accA[r][0]); g.y = f2bf(accA[r][1]);
        g.z = f2bf(accA[r][2]); g.w = f2bf(accA[r][3]);
        *(ushort4*)(Ga + (size_t)gr * 64 + tx * 4) = g;
        *(float4*)(Tb + (size_t)gr * 64 + tx * 4) =
            make_float4(accB[r][0] + bvB.x, accB[r][1] + bvB.y,
                        accB[r][2] + bvB.z, accB[r][3] + bvB.w);
      }
    }
  }
}

// ---------------------------------------------------------------------------
// Standalone dual GEMM (layer 1) — same body as fused_b's dual role.
// ---------------------------------------------------------------------------
__global__ __launch_bounds__(256) void gemm_dual2(
    const float* A0, const float* __restrict__ Wa0, const float* __restrict__ Wb0,
    const float* __restrict__ bias0, unsigned short* Ga0, float* Tb0,
    const float* A1, const float* __restrict__ Wa1, const float* __restrict__ Wb1,
    const float* __restrict__ bias1, unsigned short* Ga1, float* Tb1,
    int M)
{
  __shared__ float Ws[64 * 128];
  __shared__ float As[64 * 68];
  const int tid = threadIdx.x;
  const int half = gridDim.x >> 1;

  const float* A; const float* Wa; const float* Wb; const float* bias;
  unsigned short* Ga; float* Tb; int t0;
  if ((int)blockIdx.x < half) {
    A = A0; Wa = Wa0; Wb = Wb0; bias = bias0; Ga = Ga0; Tb = Tb0; t0 = blockIdx.x;
  } else {
    A = A1; Wa = Wa1; Wb = Wb1; bias = bias1; Ga = Ga1; Tb = Tb1; t0 = blockIdx.x - half;
  }

  for (int i = tid; i < 2048; i += 256) {
    int k = i >> 5, cg = i & 31;
    float4 v = (cg < 16) ? ((const float4*)Wa)[k * 16 + cg]
                         : ((const float4*)Wb)[k * 16 + (cg - 16)];
    ((float4*)Ws)[k * 32 + cg] = v;
  }

  const int tx = tid & 15;
  const int ty = tid >> 4;
  float4 bvB = ((const float4*)bias)[tx];

  const int ntiles = (M + 63) >> 6;
  for (int t = t0; t < ntiles; t += half) {
    const int row0 = t << 6;
    float accA[4][4] = {};
    float accB[4][4] = {};
    __syncthreads();
    for (int i = tid; i < 1024; i += 256) {
      int r = i >> 4;
      int kk = (i & 15) << 2;
      int gr = row0 + r; if (gr > M - 1) gr = M - 1;
      *(float4*)&As[r * 68 + kk] = *(const float4*)(A + (size_t)gr * 64 + kk);
    }
    __syncthreads();
    #pragma unroll 8
    for (int k = 0; k < 64; ++k) {
      float4 wa = *(const float4*)&Ws[k * 128 + tx * 4];
      float4 wb = *(const float4*)&Ws[k * 128 + 64 + tx * 4];
      float a0 = As[(ty * 4 + 0) * 68 + k];
      float a1 = As[(ty * 4 + 1) * 68 + k];
      float a2 = As[(ty * 4 + 2) * 68 + k];
      float a3 = As[(ty * 4 + 3) * 68 + k];
      accA[0][0] += a0 * wa.x; accA[0][1] += a0 * wa.y; accA[0][2] += a0 * wa.z; accA[0][3] += a0 * wa.w;
      accA[1][0] += a1 * wa.x; accA[1][1] += a1 * wa.y; accA[1][2] += a1 * wa.z; accA[1][3] += a1 * wa.w;
      accA[2][0] += a2 * wa.x; accA[2][1] += a2 * wa.y; accA[2][2] += a2 * wa.z; accA[2][3] += a2 * wa.w;
      accA[3][0] += a3 * wa.x; accA[3][1] += a3 * wa.y; accA[3][2] += a3 * wa.z; accA[3][3] += a3 * wa.w;
      accB[0][0] += a0 * wb.x; accB[0][1] += a0 * wb.y; accB[0][2] += a0 * wb.z; accB[0][3] += a0 * wb.w;
      accB[1][0] += a1 * wb.x; accB[1][1] += a1 * wb.y; accB[1][2] += a1 * wb.z; accB[1][3] += a1 * wb.w;
      accB[2][0] += a2 * wb.x; accB[2][1] += a2 * wb.y; accB[2][2] += a2 * wb.z; accB[2][3] += a2 * wb.w;
      accB[3][0] += a3 * wb.x; accB[3][1] += a3 * wb.y; accB[3][2] += a3 * wb.z; accB[3][3] += a3 * wb.w;
    }
    #pragma unroll
    for (int r = 0; r < 4; ++r) {
      int gr = row0 + ty * 4 + r;
      if (gr < M) {
        ushort4 g;
        g.x = f2bf(accA[r][0]); g.y = f2bf(accA[r][1]);
        g.z = f2bf(accA[r][2]); g.w = f2bf(accA[r][3]);
        *(ushort4*)(Ga + (size_t)gr * 64 + tx * 4) = g;
        *(float4*)(Tb + (size_t)gr * 64 + tx * 4) =
            make_float4(accB[r][0] + bvB.x, accB[r][1] + bvB.y,
                        accB[r][2] + bvB.z, accB[r][3] + bvB.w);
      }
    }
  }
}

// ---------------------------------------------------------------------------
// Fused aggregation x2 (proven body): out = relu(mean bf16 G[j,:] + T[n,:])
// ptr is int2{start,end} per node (buckets have padded capacity regions).
// ---------------------------------------------------------------------------
__global__ __launch_bounds__(256) void agg2(
    const unsigned short* __restrict__ G0, const float* T0,
    const int2* __restrict__ ptr0, const int* __restrict__ idx0, float* out0,
    const unsigned short* __restrict__ G1, const float* T1,
    const int2* __restrict__ ptr1, const int* __restrict__ idx1, float* out1,
    int n_dst)
{
  const int lane = threadIdx.x & 63;
  const int sub = lane >> 5;            // node within wave (0/1)
  const int s32 = lane & 31;
  const int k = s32 >> 4;               // edge parity slot (0/1)
  const int c4 = (s32 & 15) << 2;       // first of 4 channels this lane owns
  int wave = blockIdx.x * 4 + (threadIdx.x >> 6);
  const int nwh = (gridDim.x * 4) >> 1;
  const unsigned short* G; const float* T; const int2* ptr; const int* idx; float* out;
  if (wave < nwh) { G = G0; T = T0; ptr = ptr0; idx = idx0; out = out0; }
  else { G = G1; T = T1; ptr = ptr1; idx = idx1; out = out1; wave -= nwh; }

  for (int n0 = wave * 2; n0 < n_dst; n0 += nwh * 2) {
    const int n = n0 + sub;             // uniform across the 32-lane group
    if (n >= n_dst) continue;           // group-uniform branch
    const int2 pe = ptr[n];
    const int s = pe.x;
    const int e = pe.y;
    f32x4 t = {};
    if (k == 0)
      t = __builtin_nontemporal_load((const f32x4*)(T + (size_t)n * 64 + c4));
    float a0 = 0.f, a1 = 0.f, a2 = 0.f, a3 = 0.f;
    int i = s;
    // main: 16 edges per block; this lane covers edges i+2t+k, t=0..7
    for (; i + 16 <= e; i += 16) {
      int j0 = __builtin_nontemporal_load(idx + i + 0  + k);
      int j1 = __builtin_nontemporal_load(idx + i + 2  + k);
      int j2 = __builtin_nontemporal_load(idx + i + 4  + k);
      int j3 = __builtin_nontemporal_load(idx + i + 6  + k);
      int j4 = __builtin_nontemporal_load(idx + i + 8  + k);
      int j5 = __builtin_nontemporal_load(idx + i + 10 + k);
      int j6 = __builtin_nontemporal_load(idx + i + 12 + k);
      int j7 = __builtin_nontemporal_load(idx + i + 14 + k);
      uint2 g0 = *(const uint2*)(G + (size_t)j0 * 64 + c4);
      uint2 g1 = *(const uint2*)(G + (size_t)j1 * 64 + c4);
      uint2 g2 = *(const uint2*)(G + (size_t)j2 * 64 + c4);
      uint2 g3 = *(const uint2*)(G + (size_t)j3 * 64 + c4);
      uint2 g4 = *(const uint2*)(G + (size_t)j4 * 64 + c4);
      uint2 g5 = *(const uint2*)(G + (size_t)j5 * 64 + c4);
      uint2 g6 = *(const uint2*)(G + (size_t)j6 * 64 + c4);
      uint2 g7 = *(const uint2*)(G + (size_t)j7 * 64 + c4);
      a0 += bflo(g0.x); a1 += bfhi(g0.x); a2 += bflo(g0.y); a3 += bfhi(g0.y);
      a0 += bflo(g1.x); a1 += bfhi(g1.x); a2 += bflo(g1.y); a3 += bfhi(g1.y);
      a0 += bflo(g2.x); a1 += bfhi(g2.x); a2 += bflo(g2.y); a3 += bfhi(g2.y);
      a0 += bflo(g3.x); a1 += bfhi(g3.x); a2 += bflo(g3.y); a3 += bfhi(g3.y);
      a0 += bflo(g4.x); a1 += bfhi(g4.x); a2 += bflo(g4.y); a3 += bfhi(g4.y);
      a0 += bflo(g5.x); a1 += bfhi(g5.x); a2 += bflo(g5.y); a3 += bfhi(g5.y);
      a0 += bflo(g6.x); a1 += bfhi(g6.x); a2 += bflo(g6.y); a3 += bfhi(g6.y);
      a0 += bflo(g7.x); a1 += bfhi(g7.x); a2 += bflo(g7.y); a3 += bfhi(g7.y);
    }
    // tail: one predicated 16-edge block (fully pipelined, no serial chain)
    if (i < e) {
      const int em1 = e - 1;
      const int t0 = i + 0  + k, t1 = i + 2  + k, t2 = i + 4  + k, t3 = i + 6  + k;
      const int t4 = i + 8  + k, t5 = i + 10 + k, t6 = i + 12 + k, t7 = i + 14 + k;
      int j0 = __builtin_nontemporal_load(idx + min(t0, em1));
      int j1 = __builtin_nontemporal_load(idx + min(t1, em1));
      int j2 = __builtin_nontemporal_load(idx + min(t2, em1));
      int j3 = __builtin_nontemporal_load(idx + min(t3, em1));
      int j4 = __builtin_nontemporal_load(idx + min(t4, em1));
      int j5 = __builtin_nontemporal_load(idx + min(t5, em1));
      int j6 = __builtin_nontemporal_load(idx + min(t6, em1));
      int j7 = __builtin_nontemporal_load(idx + min(t7, em1));
      uint2 g0 = *(const uint2*)(G + (size_t)j0 * 64 + c4);
      uint2 g1 = *(const uint2*)(G + (size_t)j1 * 64 + c4);
      uint2 g2 = *(const uint2*)(G + (size_t)j2 * 64 + c4);
      uint2 g3 = *(const uint2*)(G + (size_t)j3 * 64 + c4);
      uint2 g4 = *(const uint2*)(G + (size_t)j4 * 64 + c4);
      uint2 g5 = *(const uint2*)(G + (size_t)j5 * 64 + c4);
      uint2 g6 = *(const uint2*)(G + (size_t)j6 * 64 + c4);
      uint2 g7 = *(const uint2*)(G + (size_t)j7 * 64 + c4);
      float w0 = (t0 <= em1) ? 1.f : 0.f;
      float w1 = (t1 <= em1) ? 1.f : 0.f;
      float w2 = (t2 <= em1) ? 1.f : 0.f;
      float w3 = (t3 <= em1) ? 1.f : 0.f;
      float w4 = (t4 <= em1) ? 1.f : 0.f;
      float w5 = (t5 <= em1) ? 1.f : 0.f;
      float w6 = (t6 <= em1) ? 1.f : 0.f;
      float w7 = (t7 <= em1) ? 1.f : 0.f;
      a0 = fmaf(bflo(g0.x), w0, a0); a1 = fmaf(bfhi(g0.x), w0, a1);
      a2 = fmaf(bflo(g0.y), w0, a2); a3 = fmaf(bfhi(g0.y), w0, a3);
      a0 = fmaf(bflo(g1.x), w1, a0); a1 = fmaf(bfhi(g1.x), w1, a1);
      a2 = fmaf(bflo(g1.y), w1, a2); a3 = fmaf(bfhi(g1.y), w1, a3);
      a0 = fmaf(bflo(g2.x), w2, a0); a1 = fmaf(bfhi(g2.x), w2, a1);
      a2 = fmaf(bflo(g2.y), w2, a2); a3 = fmaf(bfhi(g2.y), w2, a3);
      a0 = fmaf(bflo(g3.x), w3, a0); a1 = fmaf(bfhi(g3.x), w3, a1);
      a2 = fmaf(bflo(g3.y), w3, a2); a3 = fmaf(bfhi(g3.y), w3, a3);
      a0 = fmaf(bflo(g4.x), w4, a0); a1 = fmaf(bfhi(g4.x), w4, a1);
      a2 = fmaf(bflo(g4.y), w4, a2); a3 = fmaf(bfhi(g4.y), w4, a3);
      a0 = fmaf(bflo(g5.x), w5, a0); a1 = fmaf(bfhi(g5.x), w5, a1);
      a2 = fmaf(bflo(g5.y), w5, a2); a3 = fmaf(bfhi(g5.y), w5, a3);
      a0 = fmaf(bflo(g6.x), w6, a0); a1 = fmaf(bfhi(g6.x), w6, a1);
      a2 = fmaf(bflo(g6.y), w6, a2); a3 = fmaf(bfhi(g6.y), w6, a3);
      a0 = fmaf(bflo(g7.x), w7, a0); a1 = fmaf(bfhi(g7.x), w7, a1);
      a2 = fmaf(bflo(g7.y), w7, a2); a3 = fmaf(bfhi(g7.y), w7, a3);
    }
    // combine the two edge-parity partial sums (lane ^ 16 within each 32-group)
    a0 += __shfl_xor(a0, 16);
    a1 += __shfl_xor(a1, 16);
    a2 += __shfl_xor(a2, 16);
    a3 += __shfl_xor(a3, 16);
    const int deg = e - s;
    const float inv = 1.f / (float)(deg > 0 ? deg : 1);
    if (k == 0) {
      f32x4 o;
      o.x = fmaxf(fmaf(a0, inv, t.x), 0.f);
      o.y = fmaxf(fmaf(a1, inv, t.y), 0.f);
      o.z = fmaxf(fmaf(a2, inv, t.z), 0.f);
      o.w = fmaxf(fmaf(a3, inv, t.w), 0.f);
      __builtin_nontemporal_store(o, (f32x4*)(out + (size_t)n * 64 + c4));
    }
  }
}

// ---------------------------------------------------------------------------
extern "C" void kernel_launch(void* const* d_in, const int* in_sizes, int n_in,
                              void* d_out, int out_size, void* d_ws, size_t ws_size,
                              hipStream_t stream) {
  const float* x_user = (const float*)d_in[0];
  const float* x_item = (const float*)d_in[1];
  const int*   edge_ui = (const int*)d_in[2];   // A: dst = item
  const int*   edge_iu = (const int*)d_in[3];   // B: dst = user
  const float* Wu = (const float*)d_in[4];
  const float* bu = (const float*)d_in[5];
  const float* Wi = (const float*)d_in[6];
  const float* bi = (const float*)d_in[7];
  const float* Wl = (const float*)d_in[8];
  const float* bl = (const float*)d_in[9];
  const float* Wr = (const float*)d_in[10];

  float* outU = (float*)d_out;
  float* outI = outU + (size_t)NUSER * HID;

  char* p = (char*)d_ws;
  auto alloc = [&](size_t bytes) -> void* {
    void* r = (void*)p; p += (bytes + 255) & ~(size_t)255; return r;
  };
  float* U = (float*)alloc((size_t)NUSER * HID * 4);          // hu0
  float* I = (float*)alloc((size_t)NITEM * HID * 4);          // hi0
  unsigned short* GA = (unsigned short*)alloc((size_t)NUSER * HID * 2);
  unsigned short* GB = (unsigned short*)alloc((size_t)NITEM * HID * 2);
  // pairs UN-ALIASED (read by fill role while dual role writes GA/GB
  // in the same dispatch).
  unsigned int* pairsA = (unsigned int*)alloc((size_t)NBKT * BCAP * 4);
  unsigned int* pairsB = (unsigned int*)alloc((size_t)NBKT * BCAP * 4);
  int* curA = (int*)alloc((size_t)(2 * NBKT) * 4);
  int* curB = curA + NBKT;
  int2* ptr_ui = (int2*)alloc(((size_t)NITEM) * 8);
  int2* ptr_iu = (int2*)alloc(((size_t)NUSER) * 8);
  int* idx_ui = (int*)alloc((size_t)NBKT * BCAP * 4);
  int* idx_iu = (int*)alloc((size_t)NBKT * BCAP * 4);

  hipError_t _e = hipMemsetAsync(curA, 0, (size_t)(2 * NBKT) * 4, stream); (void)_e;

  const int AGG_B = 2 * ((NUSER / 2 + 3) / 4); // 25000

  const float* Wl00 = Wl;             const float* Wl01 = Wl + 4096;
  const float* Wl10 = Wl + 2 * 4096;  const float* Wl11 = Wl + 3 * 4096;
  const float* Wr00 = Wr;             const float* Wr01 = Wr + 4096;
  const float* Wr10 = Wr + 2 * 4096;  const float* Wr11 = Wr + 3 * 4096;
  const float* bl00 = bl;             const float* bl01 = bl + 64;
  const float* bl10 = bl + 128;       const float* bl11 = bl + 192;

  // ---- dispatch 1: partition (CSR pass 1) || input linears ----
  fused_a<<<2 * NCHUNK + 1152, 256, 0, stream>>>(
      edge_ui, edge_ui + NEDGE, curA, pairsA,
      edge_iu, edge_iu + NEDGE, curB, pairsB, NEDGE,
      x_user, Wu, bu, U,
      x_item, Wi, bi, I, NUSER,
      2 * NCHUNK);

  // ---- dispatch 2: bucket_fill (CSR pass 2) || dual GEMM layer 0 ----
  fused_b<<<2 * NBKT + 1536, 256, 0, stream>>>(
      pairsA, curA, ptr_ui, idx_ui,
      pairsB, curB, ptr_iu, idx_iu, NITEM,
      U, Wl00, Wr01, bl01, GA, outU,
      I, Wl01, Wr00, bl00, GB, outI,
      NUSER, 2 * NBKT);

  // ---- dispatch 3: aggregation layer 0 ----
  agg2<<<AGG_B, 256, 0, stream>>>(GA, outI, ptr_ui, idx_ui, outI,
                                  GB, outU, ptr_iu, idx_iu, outU, NITEM);

  // ---- dispatch 4: dual GEMM layer 1 ----
  gemm_dual2<<<1536, 256, 0, stream>>>(outI, Wl11, Wr10, bl10, GA, outI,
                                       outU, Wl10, Wr11, bl11, GB, outU,
                                       NITEM);

  // ---- dispatch 5: aggregation layer 1 ----
  agg2<<<AGG_B, 256, 0, stream>>>(GA, outU, ptr_iu, idx_iu, outU,
                                  GB, outI, ptr_ui, idx_ui, outI, NUSER);
}

// Round 11
// 545.788 us; speedup vs baseline: 1.0374x; 1.0374x over previous
//
#include <hip/hip_runtime.h>

#define NUSER 100000
#define NITEM 100000
#define NEDGE 1600000
#define HID 64
#define NPB 256                 // nodes per bucket (pow2: bucket = dst>>8)
#define NBKT 391                // ceil(100000/256)
#define BCAP 5120               // fixed bucket capacity (mean 4096, sigma~64)
#define ACHUNK 8192             // partition chunk (edges)
#define NCHUNK ((NEDGE + ACHUNK - 1) / ACHUNK)   // 196 per edge type
#define ATS 66                  // transposed-As stride (floats): 8B-aligned, 4-way stage conflict

typedef float f32x4 __attribute__((ext_vector_type(4)));
typedef float f32x2 __attribute__((ext_vector_type(2)));

__device__ __forceinline__ unsigned short f2bf(float x) {
  unsigned int u; __builtin_memcpy(&u, &x, 4);
  u += 0x7fffu + ((u >> 16) & 1u);
  return (unsigned short)(u >> 16);
}
__device__ __forceinline__ float bflo(unsigned int u) {
  unsigned int v = u << 16; float f; __builtin_memcpy(&f, &v, 4); return f;
}
__device__ __forceinline__ float bfhi(unsigned int u) {
  unsigned int v = u & 0xffff0000u; float f; __builtin_memcpy(&f, &v, 4); return f;
}

// ---------------------------------------------------------------------------
// Fused input linears (both node types, one dispatch, parity grid-split):
// C[M,64] = relu(A[M,K] @ W[K,64] + bias), runtime K (128 or 64).
// As stored TRANSPOSED [k][row] so the 4 row-values per k are one b64 pair.
// ---------------------------------------------------------------------------
__global__ __launch_bounds__(256) void gemm_in2(
    const float* __restrict__ A0, const float* __restrict__ W0,
    const float* __restrict__ bias0, float* __restrict__ C0,
    const float* __restrict__ A1, const float* __restrict__ W1,
    const float* __restrict__ bias1, float* __restrict__ C1, int M)
{
  __shared__ float Ws[128 * 64];
  __shared__ float As[64 * ATS];    // [k_local][row]
  const int tid = threadIdx.x;

  const int side = blockIdx.x & 1;
  const int t0 = blockIdx.x >> 1;
  const int nb = gridDim.x >> 1;
  const float* A; const float* W; const float* bias; float* C; int K;
  if (side == 0) { A = A0; W = W0; bias = bias0; C = C0; K = 128; }
  else           { A = A1; W = W1; bias = bias1; C = C1; K = 64; }

  for (int i = tid; i < K * 16; i += 256)
    ((float4*)Ws)[i] = ((const float4*)W)[i];

  const int tx = tid & 15;
  const int ty = tid >> 4;
  const int ty4 = ty * 4;
  float4 bv = ((const float4*)bias)[tx];

  const int ntiles = (M + 63) >> 6;
  for (int t = t0; t < ntiles; t += nb) {
    const int row0 = t << 6;
    float acc[4][4] = {};
    for (int kb = 0; kb < K; kb += 64) {
      __syncthreads();
      for (int i = tid; i < 1024; i += 256) {
        int r = i >> 4;
        int kk = (i & 15) << 2;
        int gr = row0 + r; if (gr > M - 1) gr = M - 1;
        float4 v = *(const float4*)(A + (size_t)gr * K + kb + kk);
        As[(kk + 0) * ATS + r] = v.x;
        As[(kk + 1) * ATS + r] = v.y;
        As[(kk + 2) * ATS + r] = v.z;
        As[(kk + 3) * ATS + r] = v.w;
      }
      __syncthreads();
      #pragma unroll 8
      for (int k = 0; k < 64; ++k) {
        float4 w = *(const float4*)&Ws[(kb + k) * 64 + tx * 4];
        f32x2 a01 = *(const f32x2*)&As[k * ATS + ty4];
        f32x2 a23 = *(const f32x2*)&As[k * ATS + ty4 + 2];
        float a0 = a01[0], a1 = a01[1], a2 = a23[0], a3 = a23[1];
        acc[0][0] += a0 * w.x; acc[0][1] += a0 * w.y; acc[0][2] += a0 * w.z; acc[0][3] += a0 * w.w;
        acc[1][0] += a1 * w.x; acc[1][1] += a1 * w.y; acc[1][2] += a1 * w.z; acc[1][3] += a1 * w.w;
        acc[2][0] += a2 * w.x; acc[2][1] += a2 * w.y; acc[2][2] += a2 * w.z; acc[2][3] += a2 * w.w;
        acc[3][0] += a3 * w.x; acc[3][1] += a3 * w.y; acc[3][2] += a3 * w.z; acc[3][3] += a3 * w.w;
      }
    }
    #pragma unroll
    for (int r = 0; r < 4; ++r) {
      int gr = row0 + ty4 + r;
      if (gr < M) {
        float4 o = make_float4(fmaxf(acc[r][0] + bv.x, 0.f), fmaxf(acc[r][1] + bv.y, 0.f),
                               fmaxf(acc[r][2] + bv.z, 0.f), fmaxf(acc[r][3] + bv.w, 0.f));
        *(float4*)(C + (size_t)gr * 64 + tx * 4) = o;
      }
    }
  }
}

// ---------------------------------------------------------------------------
// Fused dual GEMM x2 (both node types in one dispatch, grid split):
//   Ga = bf16(A @ Wa) ; Tb = A @ Wb + bias.  Tb may alias A (row-wise safe).
// As stored TRANSPOSED [k][row]; persistent half-grid per side.
// ---------------------------------------------------------------------------
__global__ __launch_bounds__(256) void gemm_dual2(
    const float* A0, const float* __restrict__ Wa0, const float* __restrict__ Wb0,
    const float* __restrict__ bias0, unsigned short* Ga0, float* Tb0,
    const float* A1, const float* __restrict__ Wa1, const float* __restrict__ Wb1,
    const float* __restrict__ bias1, unsigned short* Ga1, float* Tb1,
    int M)
{
  __shared__ float Ws[64 * 128];
  __shared__ float As[64 * ATS];    // [k][row]
  const int tid = threadIdx.x;
  const int half = gridDim.x >> 1;

  const float* A; const float* Wa; const float* Wb; const float* bias;
  unsigned short* Ga; float* Tb; int t0;
  if ((int)blockIdx.x < half) {
    A = A0; Wa = Wa0; Wb = Wb0; bias = bias0; Ga = Ga0; Tb = Tb0; t0 = blockIdx.x;
  } else {
    A = A1; Wa = Wa1; Wb = Wb1; bias = bias1; Ga = Ga1; Tb = Tb1; t0 = blockIdx.x - half;
  }

  for (int i = tid; i < 2048; i += 256) {
    int k = i >> 5, cg = i & 31;
    float4 v = (cg < 16) ? ((const float4*)Wa)[k * 16 + cg]
                         : ((const float4*)Wb)[k * 16 + (cg - 16)];
    ((float4*)Ws)[k * 32 + cg] = v;
  }

  const int tx = tid & 15;
  const int ty = tid >> 4;
  const int ty4 = ty * 4;
  float4 bvB = ((const float4*)bias)[tx];

  const int ntiles = (M + 63) >> 6;
  for (int t = t0; t < ntiles; t += half) {
    const int row0 = t << 6;
    float accA[4][4] = {};
    float accB[4][4] = {};
    __syncthreads();
    for (int i = tid; i < 1024; i += 256) {
      int r = i >> 4;
      int kk = (i & 15) << 2;
      int gr = row0 + r; if (gr > M - 1) gr = M - 1;
      float4 v = *(const float4*)(A + (size_t)gr * 64 + kk);
      As[(kk + 0) * ATS + r] = v.x;
      As[(kk + 1) * ATS + r] = v.y;
      As[(kk + 2) * ATS + r] = v.z;
      As[(kk + 3) * ATS + r] = v.w;
    }
    __syncthreads();
    #pragma unroll 8
    for (int k = 0; k < 64; ++k) {
      float4 wa = *(const float4*)&Ws[k * 128 + tx * 4];
      float4 wb = *(const float4*)&Ws[k * 128 + 64 + tx * 4];
      f32x2 a01 = *(const f32x2*)&As[k * ATS + ty4];
      f32x2 a23 = *(const f32x2*)&As[k * ATS + ty4 + 2];
      float a0 = a01[0], a1 = a01[1], a2 = a23[0], a3 = a23[1];
      accA[0][0] += a0 * wa.x; accA[0][1] += a0 * wa.y; accA[0][2] += a0 * wa.z; accA[0][3] += a0 * wa.w;
      accA[1][0] += a1 * wa.x; accA[1][1] += a1 * wa.y; accA[1][2] += a1 * wa.z; accA[1][3] += a1 * wa.w;
      accA[2][0] += a2 * wa.x; accA[2][1] += a2 * wa.y; accA[2][2] += a2 * wa.z; accA[2][3] += a2 * wa.w;
      accA[3][0] += a3 * wa.x; accA[3][1] += a3 * wa.y; accA[3][2] += a3 * wa.z; accA[3][3] += a3 * wa.w;
      accB[0][0] += a0 * wb.x; accB[0][1] += a0 * wb.y; accB[0][2] += a0 * wb.z; accB[0][3] += a0 * wb.w;
      accB[1][0] += a1 * wb.x; accB[1][1] += a1 * wb.y; accB[1][2] += a1 * wb.z; accB[1][3] += a1 * wb.w;
      accB[2][0] += a2 * wb.x; accB[2][1] += a2 * wb.y; accB[2][2] += a2 * wb.z; accB[2][3] += a2 * wb.w;
      accB[3][0] += a3 * wb.x; accB[3][1] += a3 * wb.y; accB[3][2] += a3 * wb.z; accB[3][3] += a3 * wb.w;
    }
    #pragma unroll
    for (int r = 0; r < 4; ++r) {
      int gr = row0 + ty4 + r;
      if (gr < M) {
        ushort4 g;
        g.x = f2bf(accA[r][0]); g.y = f2bf(accA[r][1]);
        g.z = f2bf(accA[r][2]); g.w = f2bf(accA[r][3]);
        *(ushort4*)(Ga + (size_t)gr * 64 + tx * 4) = g;
        *(float4*)(Tb + (size_t)gr * 64 + tx * 4) =
            make_float4(accB[r][0] + bvB.x, accB[r][1] + bvB.y,
                        accB[r][2] + bvB.z, accB[r][3] + bvB.w);
      }
    }
  }
}

// ---------------------------------------------------------------------------
// Fused aggregation x2 (proven body): out = relu(mean bf16 G[j,:] + T[n,:])
// ptr is int2{start,end} per node (buckets have padded capacity regions).
// ---------------------------------------------------------------------------
__global__ __launch_bounds__(256) void agg2(
    const unsigned short* __restrict__ G0, const float* T0,
    const int2* __restrict__ ptr0, const int* __restrict__ idx0, float* out0,
    const unsigned short* __restrict__ G1, const float* T1,
    const int2* __restrict__ ptr1, const int* __restrict__ idx1, float* out1,
    int n_dst)
{
  const int lane = threadIdx.x & 63;
  const int sub = lane >> 5;            // node within wave (0/1)
  const int s32 = lane & 31;
  const int k = s32 >> 4;               // edge parity slot (0/1)
  const int c4 = (s32 & 15) << 2;       // first of 4 channels this lane owns
  int wave = blockIdx.x * 4 + (threadIdx.x >> 6);
  const int nwh = (gridDim.x * 4) >> 1;
  const unsigned short* G; const float* T; const int2* ptr; const int* idx; float* out;
  if (wave < nwh) { G = G0; T = T0; ptr = ptr0; idx = idx0; out = out0; }
  else { G = G1; T = T1; ptr = ptr1; idx = idx1; out = out1; wave -= nwh; }

  for (int n0 = wave * 2; n0 < n_dst; n0 += nwh * 2) {
    const int n = n0 + sub;             // uniform across the 32-lane group
    if (n >= n_dst) continue;           // group-uniform branch
    const int2 pe = ptr[n];
    const int s = pe.x;
    const int e = pe.y;
    f32x4 t = {};
    if (k == 0)
      t = __builtin_nontemporal_load((const f32x4*)(T + (size_t)n * 64 + c4));
    float a0 = 0.f, a1 = 0.f, a2 = 0.f, a3 = 0.f;
    int i = s;
    // main: 16 edges per block; this lane covers edges i+2t+k, t=0..7
    for (; i + 16 <= e; i += 16) {
      int j0 = __builtin_nontemporal_load(idx + i + 0  + k);
      int j1 = __builtin_nontemporal_load(idx + i + 2  + k);
      int j2 = __builtin_nontemporal_load(idx + i + 4  + k);
      int j3 = __builtin_nontemporal_load(idx + i + 6  + k);
      int j4 = __builtin_nontemporal_load(idx + i + 8  + k);
      int j5 = __builtin_nontemporal_load(idx + i + 10 + k);
      int j6 = __builtin_nontemporal_load(idx + i + 12 + k);
      int j7 = __builtin_nontemporal_load(idx + i + 14 + k);
      uint2 g0 = *(const uint2*)(G + (size_t)j0 * 64 + c4);
      uint2 g1 = *(const uint2*)(G + (size_t)j1 * 64 + c4);
      uint2 g2 = *(const uint2*)(G + (size_t)j2 * 64 + c4);
      uint2 g3 = *(const uint2*)(G + (size_t)j3 * 64 + c4);
      uint2 g4 = *(const uint2*)(G + (size_t)j4 * 64 + c4);
      uint2 g5 = *(const uint2*)(G + (size_t)j5 * 64 + c4);
      uint2 g6 = *(const uint2*)(G + (size_t)j6 * 64 + c4);
      uint2 g7 = *(const uint2*)(G + (size_t)j7 * 64 + c4);
      a0 += bflo(g0.x); a1 += bfhi(g0.x); a2 += bflo(g0.y); a3 += bfhi(g0.y);
      a0 += bflo(g1.x); a1 += bfhi(g1.x); a2 += bflo(g1.y); a3 += bfhi(g1.y);
      a0 += bflo(g2.x); a1 += bfhi(g2.x); a2 += bflo(g2.y); a3 += bfhi(g2.y);
      a0 += bflo(g3.x); a1 += bfhi(g3.x); a2 += bflo(g3.y); a3 += bfhi(g3.y);
      a0 += bflo(g4.x); a1 += bfhi(g4.x); a2 += bflo(g4.y); a3 += bfhi(g4.y);
      a0 += bflo(g5.x); a1 += bfhi(g5.x); a2 += bflo(g5.y); a3 += bfhi(g5.y);
      a0 += bflo(g6.x); a1 += bfhi(g6.x); a2 += bflo(g6.y); a3 += bfhi(g6.y);
      a0 += bflo(g7.x); a1 += bfhi(g7.x); a2 += bflo(g7.y); a3 += bfhi(g7.y);
    }
    // tail: one predicated 16-edge block (fully pipelined, no serial chain)
    if (i < e) {
      const int em1 = e - 1;
      const int t0 = i + 0  + k, t1 = i + 2  + k, t2 = i + 4  + k, t3 = i + 6  + k;
      const int t4 = i + 8  + k, t5 = i + 10 + k, t6 = i + 12 + k, t7 = i + 14 + k;
      int j0 = __builtin_nontemporal_load(idx + min(t0, em1));
      int j1 = __builtin_nontemporal_load(idx + min(t1, em1));
      int j2 = __builtin_nontemporal_load(idx + min(t2, em1));
      int j3 = __builtin_nontemporal_load(idx + min(t3, em1));
      int j4 = __builtin_nontemporal_load(idx + min(t4, em1));
      int j5 = __builtin_nontemporal_load(idx + min(t5, em1));
      int j6 = __builtin_nontemporal_load(idx + min(t6, em1));
      int j7 = __builtin_nontemporal_load(idx + min(t7, em1));
      uint2 g0 = *(const uint2*)(G + (size_t)j0 * 64 + c4);
      uint2 g1 = *(const uint2*)(G + (size_t)j1 * 64 + c4);
      uint2 g2 = *(const uint2*)(G + (size_t)j2 * 64 + c4);
      uint2 g3 = *(const uint2*)(G + (size_t)j3 * 64 + c4);
      uint2 g4 = *(const uint2*)(G + (size_t)j4 * 64 + c4);
      uint2 g5 = *(const uint2*)(G + (size_t)j5 * 64 + c4);
      uint2 g6 = *(const uint2*)(G + (size_t)j6 * 64 + c4);
      uint2 g7 = *(const uint2*)(G + (size_t)j7 * 64 + c4);
      float w0 = (t0 <= em1) ? 1.f : 0.f;
      float w1 = (t1 <= em1) ? 1.f : 0.f;
      float w2 = (t2 <= em1) ? 1.f : 0.f;
      float w3 = (t3 <= em1) ? 1.f : 0.f;
      float w4 = (t4 <= em1) ? 1.f : 0.f;
      float w5 = (t5 <= em1) ? 1.f : 0.f;
      float w6 = (t6 <= em1) ? 1.f : 0.f;
      float w7 = (t7 <= em1) ? 1.f : 0.f;
      a0 = fmaf(bflo(g0.x), w0, a0); a1 = fmaf(bfhi(g0.x), w0, a1);
      a2 = fmaf(bflo(g0.y), w0, a2); a3 = fmaf(bfhi(g0.y), w0, a3);
      a0 = fmaf(bflo(g1.x), w1, a0); a1 = fmaf(bfhi(g1.x), w1, a1);
      a2 = fmaf(bflo(g1.y), w1, a2); a3 = fmaf(bfhi(g1.y), w1, a3);
      a0 = fmaf(bflo(g2.x), w2, a0); a1 = fmaf(bfhi(g2.x), w2, a1);
      a2 = fmaf(bflo(g2.y), w2, a2); a3 = fmaf(bfhi(g2.y), w2, a3);
      a0 = fmaf(bflo(g3.x), w3, a0); a1 = fmaf(bfhi(g3.x), w3, a1);
      a2 = fmaf(bflo(g3.y), w3, a2); a3 = fmaf(bfhi(g3.y), w3, a3);
      a0 = fmaf(bflo(g4.x), w4, a0); a1 = fmaf(bfhi(g4.x), w4, a1);
      a2 = fmaf(bflo(g4.y), w4, a2); a3 = fmaf(bfhi(g4.y), w4, a3);
      a0 = fmaf(bflo(g5.x), w5, a0); a1 = fmaf(bfhi(g5.x), w5, a1);
      a2 = fmaf(bflo(g5.y), w5, a2); a3 = fmaf(bfhi(g5.y), w5, a3);
      a0 = fmaf(bflo(g6.x), w6, a0); a1 = fmaf(bfhi(g6.x), w6, a1);
      a2 = fmaf(bflo(g6.y), w6, a2); a3 = fmaf(bfhi(g6.y), w6, a3);
      a0 = fmaf(bflo(g7.x), w7, a0); a1 = fmaf(bfhi(g7.x), w7, a1);
      a2 = fmaf(bflo(g7.y), w7, a2); a3 = fmaf(bfhi(g7.y), w7, a3);
    }
    // combine the two edge-parity partial sums (lane ^ 16 within each 32-group)
    a0 += __shfl_xor(a0, 16);
    a1 += __shfl_xor(a1, 16);
    a2 += __shfl_xor(a2, 16);
    a3 += __shfl_xor(a3, 16);
    const int deg = e - s;
    const float inv = 1.f / (float)(deg > 0 ? deg : 1);
    if (k == 0) {
      f32x4 o;
      o.x = fmaxf(fmaf(a0, inv, t.x), 0.f);
      o.y = fmaxf(fmaf(a1, inv, t.y), 0.f);
      o.z = fmaxf(fmaf(a2, inv, t.z), 0.f);
      o.w = fmaxf(fmaf(a3, inv, t.w), 0.f);
      __builtin_nontemporal_store(o, (f32x4*)(out + (size_t)n * 64 + c4));
    }
  }
}

// ---------------------------------------------------------------------------
// CSR build, 2 dispatches (fixed-capacity buckets, no hist/scan passes).
// K2: partition edges into bucket regions [b*BCAP, b*BCAP+cnt).
// ---------------------------------------------------------------------------
__global__ __launch_bounds__(256) void partition2(
    const int* __restrict__ srcA, const int* __restrict__ dstA, int* curA, unsigned int* pairsA,
    const int* __restrict__ srcB, const int* __restrict__ dstB, int* curB, unsigned int* pairsB,
    int E)
{
  __shared__ int h[NBKT];
  __shared__ int c[NBKT];
  const int half = gridDim.x >> 1;   // chunks per type
  const bool isB = (int)blockIdx.x >= half;
  const int chunk = isB ? blockIdx.x - half : blockIdx.x;
  const int* src = isB ? srcB : srcA;
  const int* dst = isB ? dstB : dstA;
  int* cur = isB ? curB : curA;
  unsigned int* pairs = isB ? pairsB : pairsA;
  const int e0 = chunk * ACHUNK;
  const int e1 = min(e0 + ACHUNK, E);
  for (int i = threadIdx.x; i < NBKT; i += 256) h[i] = 0;
  __syncthreads();
  for (int e = e0 + (int)threadIdx.x; e < e1; e += 256)
    atomicAdd(&h[__builtin_nontemporal_load(dst + e) >> 8], 1);
  __syncthreads();
  for (int i = threadIdx.x; i < NBKT; i += 256) {
    int v = h[i];
    if (v) c[i] = i * BCAP + atomicAdd(&cur[i], v);
  }
  __syncthreads();
  for (int e = e0 + (int)threadIdx.x; e < e1; e += 256) {
    int d = __builtin_nontemporal_load(dst + e);
    int s = __builtin_nontemporal_load(src + e);
    int b = d >> 8;
    int p = atomicAdd(&c[b], 1);
    pairs[p] = ((unsigned int)(d & 255) << 24) | (unsigned int)s;
  }
}

// K3: per-bucket CSR finalize: degree hist (LDS) -> scan -> int2 ptr write ->
// scatter src into the bucket's own idx region via LDS cursors.
__global__ __launch_bounds__(256) void bucket_fill(
    const unsigned int* __restrict__ pairsA, const int* __restrict__ cntA,
    int2* __restrict__ ptrA, int* __restrict__ idxA,
    const unsigned int* __restrict__ pairsB, const int* __restrict__ cntB,
    int2* __restrict__ ptrB, int* __restrict__ idxB, int n)
{
  __shared__ int h[NPB];
  __shared__ int cur[NPB];
  const bool isB = (int)blockIdx.x >= NBKT;
  const int b = isB ? blockIdx.x - NBKT : blockIdx.x;
  const unsigned int* pairs = isB ? pairsB : pairsA;
  const int* cnt = isB ? cntB : cntA;
  int2* ptr = isB ? ptrB : ptrA;
  int* idx = isB ? idxB : idxA;
  const int ebase = b * BCAP;
  const int eend = ebase + min(cnt[b], BCAP);
  const int t = threadIdx.x;
  h[t] = 0;
  __syncthreads();
  for (int e = ebase + t; e < eend; e += 256)
    atomicAdd(&h[pairs[e] >> 24], 1);
  __syncthreads();
  const int v = h[t];
  __syncthreads();
  for (int off = 1; off < 256; off <<= 1) {
    int x = 0;
    if (t >= off) x = h[t - off];
    __syncthreads();
    if (t >= off) h[t] += x;
    __syncthreads();
  }
  const int excl = h[t] - v;
  const int gnode = b * NPB + t;
  if (gnode < n) ptr[gnode] = make_int2(ebase + excl, ebase + excl + v);
  cur[t] = excl;
  __syncthreads();
  for (int e = ebase + t; e < eend; e += 256) {
    unsigned int pk = pairs[e];
    int p = atomicAdd(&cur[pk >> 24], 1);
    idx[ebase + p] = (int)(pk & 0xFFFFFFu);
  }
}

// ---------------------------------------------------------------------------
extern "C" void kernel_launch(void* const* d_in, const int* in_sizes, int n_in,
                              void* d_out, int out_size, void* d_ws, size_t ws_size,
                              hipStream_t stream) {
  const float* x_user = (const float*)d_in[0];
  const float* x_item = (const float*)d_in[1];
  const int*   edge_ui = (const int*)d_in[2];   // A: dst = item
  const int*   edge_iu = (const int*)d_in[3];   // B: dst = user
  const float* Wu = (const float*)d_in[4];
  const float* bu = (const float*)d_in[5];
  const float* Wi = (const float*)d_in[6];
  const float* bi = (const float*)d_in[7];
  const float* Wl = (const float*)d_in[8];
  const float* bl = (const float*)d_in[9];
  const float* Wr = (const float*)d_in[10];

  float* outU = (float*)d_out;
  float* outI = outU + (size_t)NUSER * HID;

  char* p = (char*)d_ws;
  auto alloc = [&](size_t bytes) -> void* {
    void* r = (void*)p; p += (bytes + 255) & ~(size_t)255; return r;
  };
  float* U = (float*)alloc((size_t)NUSER * HID * 4);          // hu0
  float* I = (float*)alloc((size_t)NITEM * HID * 4);          // hi0
  unsigned short* GA = (unsigned short*)alloc((size_t)NUSER * HID * 2);
  unsigned short* GB = (unsigned short*)alloc((size_t)NITEM * HID * 2);
  // pairs buffers alias GA/GB (NBKT*BCAP*4 = 8.0MB <= 12.8MB each): dead
  // before the first gemm_dual2 writes GA/GB.
  unsigned int* pairsA = (unsigned int*)GA;
  unsigned int* pairsB = (unsigned int*)GB;
  // cur: ONE carve, memset zeroed exactly.
  int* curA = (int*)alloc((size_t)(2 * NBKT) * 4);
  int* curB = curA + NBKT;
  int2* ptr_ui = (int2*)alloc(((size_t)NITEM) * 8);
  int2* ptr_iu = (int2*)alloc(((size_t)NUSER) * 8);
  int* idx_ui = (int*)alloc((size_t)NBKT * BCAP * 4);
  int* idx_iu = (int*)alloc((size_t)NBKT * BCAP * 4);

  // ---- CSR build: memset + 2 dispatches ----
  hipError_t _e = hipMemsetAsync(curA, 0, (size_t)(2 * NBKT) * 4, stream); (void)_e;
  partition2<<<2 * NCHUNK, 256, 0, stream>>>(
      edge_ui, edge_ui + NEDGE, curA, pairsA,
      edge_iu, edge_iu + NEDGE, curB, pairsB, NEDGE);
  bucket_fill<<<2 * NBKT, 256, 0, stream>>>(pairsA, curA, ptr_ui, idx_ui,
                                            pairsB, curB, ptr_iu, idx_iu, NITEM);

  const int AGG_B = 2 * ((NUSER / 2 + 3) / 4); // 25000

  const float* Wl00 = Wl;             const float* Wl01 = Wl + 4096;
  const float* Wl10 = Wl + 2 * 4096;  const float* Wl11 = Wl + 3 * 4096;
  const float* Wr00 = Wr;             const float* Wr01 = Wr + 4096;
  const float* Wr10 = Wr + 2 * 4096;  const float* Wr11 = Wr + 3 * 4096;
  const float* bl00 = bl;             const float* bl01 = bl + 64;
  const float* bl10 = bl + 128;       const float* bl11 = bl + 192;

  // ---- input linears (one fused dispatch, parity split) ----
  gemm_in2<<<1152, 256, 0, stream>>>(x_user, Wu, bu, U,
                                     x_item, Wi, bi, I, NUSER);

  // ---- layer 0 ----
  gemm_dual2<<<1536, 256, 0, stream>>>(U, Wl00, Wr01, bl01, GA, outU,
                                       I, Wl01, Wr00, bl00, GB, outI,
                                       NUSER);
  agg2<<<AGG_B, 256, 0, stream>>>(GA, outI, ptr_ui, idx_ui, outI,
                                  GB, outU, ptr_iu, idx_iu, outU, NITEM);

  // ---- layer 1 ----
  gemm_dual2<<<1536, 256, 0, stream>>>(outI, Wl11, Wr10, bl10, GA, outI,
                                       outU, Wl10, Wr11, bl11, GB, outU,
                                       NITEM);
  agg2<<<AGG_B, 256, 0, stream>>>(GA, outU, ptr_iu, idx_iu, outU,
                                  GB, outI, ptr_ui, idx_ui, outI, NUSER);
}

// Round 12
// 540.568 us; speedup vs baseline: 1.0475x; 1.0097x over previous
//
#include <hip/hip_runtime.h>

#define NUSER 100000
#define NITEM 100000
#define NEDGE 1600000
#define HID 64
#define NPB 256                 // nodes per bucket (pow2: bucket = dst>>8)
#define NBKT 391                // ceil(100000/256)
#define BCAP 5120               // fixed bucket capacity (mean 4096, sigma~64)
#define ACHUNK 8192             // partition chunk (edges)
#define NCHUNK ((NEDGE + ACHUNK - 1) / ACHUNK)   // 196 per edge type

typedef float f32x4 __attribute__((ext_vector_type(4)));

__device__ __forceinline__ unsigned short f2bf(float x) {
  unsigned int u; __builtin_memcpy(&u, &x, 4);
  u += 0x7fffu + ((u >> 16) & 1u);
  return (unsigned short)(u >> 16);
}
__device__ __forceinline__ float bflo(unsigned int u) {
  unsigned int v = u << 16; float f; __builtin_memcpy(&f, &v, 4); return f;
}
__device__ __forceinline__ float bfhi(unsigned int u) {
  unsigned int v = u & 0xffff0000u; float f; __builtin_memcpy(&f, &v, 4); return f;
}

// ---------------------------------------------------------------------------
// Fused input linears (both node types, one dispatch, parity grid-split):
// C[M,64] = relu(A[M,K] @ W[K,64] + bias), runtime K (128 or 64).
// ---------------------------------------------------------------------------
__global__ __launch_bounds__(256) void gemm_in2(
    const float* __restrict__ A0, const float* __restrict__ W0,
    const float* __restrict__ bias0, float* __restrict__ C0,
    const float* __restrict__ A1, const float* __restrict__ W1,
    const float* __restrict__ bias1, float* __restrict__ C1, int M)
{
  __shared__ float Ws[128 * 64];
  __shared__ float As[64 * 68];
  const int tid = threadIdx.x;

  const int side = blockIdx.x & 1;
  const int t0 = blockIdx.x >> 1;
  const int nb = gridDim.x >> 1;
  const float* A; const float* W; const float* bias; float* C; int K;
  if (side == 0) { A = A0; W = W0; bias = bias0; C = C0; K = 128; }
  else           { A = A1; W = W1; bias = bias1; C = C1; K = 64; }

  for (int i = tid; i < K * 16; i += 256)
    ((float4*)Ws)[i] = ((const float4*)W)[i];

  const int tx = tid & 15;
  const int ty = tid >> 4;
  float4 bv = ((const float4*)bias)[tx];

  const int ntiles = (M + 63) >> 6;
  for (int t = t0; t < ntiles; t += nb) {
    const int row0 = t << 6;
    float acc[4][4] = {};
    for (int kb = 0; kb < K; kb += 64) {
      __syncthreads();
      for (int i = tid; i < 1024; i += 256) {
        int r = i >> 4;
        int kk = (i & 15) << 2;
        int gr = row0 + r; if (gr > M - 1) gr = M - 1;
        *(float4*)&As[r * 68 + kk] = *(const float4*)(A + (size_t)gr * K + kb + kk);
      }
      __syncthreads();
      #pragma unroll 8
      for (int k = 0; k < 64; ++k) {
        float4 w = *(const float4*)&Ws[(kb + k) * 64 + tx * 4];
        float a0 = As[(ty * 4 + 0) * 68 + k];
        float a1 = As[(ty * 4 + 1) * 68 + k];
        float a2 = As[(ty * 4 + 2) * 68 + k];
        float a3 = As[(ty * 4 + 3) * 68 + k];
        acc[0][0] += a0 * w.x; acc[0][1] += a0 * w.y; acc[0][2] += a0 * w.z; acc[0][3] += a0 * w.w;
        acc[1][0] += a1 * w.x; acc[1][1] += a1 * w.y; acc[1][2] += a1 * w.z; acc[1][3] += a1 * w.w;
        acc[2][0] += a2 * w.x; acc[2][1] += a2 * w.y; acc[2][2] += a2 * w.z; acc[2][3] += a2 * w.w;
        acc[3][0] += a3 * w.x; acc[3][1] += a3 * w.y; acc[3][2] += a3 * w.z; acc[3][3] += a3 * w.w;
      }
    }
    #pragma unroll
    for (int r = 0; r < 4; ++r) {
      int gr = row0 + ty * 4 + r;
      if (gr < M) {
        float4 o = make_float4(fmaxf(acc[r][0] + bv.x, 0.f), fmaxf(acc[r][1] + bv.y, 0.f),
                               fmaxf(acc[r][2] + bv.z, 0.f), fmaxf(acc[r][3] + bv.w, 0.f));
        *(float4*)(C + (size_t)gr * 64 + tx * 4) = o;
      }
    }
  }
}

// ---------------------------------------------------------------------------
// Fused dual GEMM x2 (both node types in one dispatch, grid split):
//   Ga = bf16(A @ Wa) ; Tb = A @ Wb + bias.  Tb may alias A (row-wise safe).
// PERSISTENT: half-grid per side, Ws loaded once per block.
// ---------------------------------------------------------------------------
__global__ __launch_bounds__(256) void gemm_dual2(
    const float* A0, const float* __restrict__ Wa0, const float* __restrict__ Wb0,
    const float* __restrict__ bias0, unsigned short* Ga0, float* Tb0,
    const float* A1, const float* __restrict__ Wa1, const float* __restrict__ Wb1,
    const float* __restrict__ bias1, unsigned short* Ga1, float* Tb1,
    int M)
{
  __shared__ float Ws[64 * 128];
  __shared__ float As[64 * 68];
  const int tid = threadIdx.x;
  const int half = gridDim.x >> 1;

  const float* A; const float* Wa; const float* Wb; const float* bias;
  unsigned short* Ga; float* Tb; int t0;
  if ((int)blockIdx.x < half) {
    A = A0; Wa = Wa0; Wb = Wb0; bias = bias0; Ga = Ga0; Tb = Tb0; t0 = blockIdx.x;
  } else {
    A = A1; Wa = Wa1; Wb = Wb1; bias = bias1; Ga = Ga1; Tb = Tb1; t0 = blockIdx.x - half;
  }

  for (int i = tid; i < 2048; i += 256) {
    int k = i >> 5, cg = i & 31;
    float4 v = (cg < 16) ? ((const float4*)Wa)[k * 16 + cg]
                         : ((const float4*)Wb)[k * 16 + (cg - 16)];
    ((float4*)Ws)[k * 32 + cg] = v;
  }

  const int tx = tid & 15;
  const int ty = tid >> 4;
  float4 bvB = ((const float4*)bias)[tx];

  const int ntiles = (M + 63) >> 6;
  for (int t = t0; t < ntiles; t += half) {
    const int row0 = t << 6;
    float accA[4][4] = {};
    float accB[4][4] = {};
    __syncthreads();
    for (int i = tid; i < 1024; i += 256) {
      int r = i >> 4;
      int kk = (i & 15) << 2;
      int gr = row0 + r; if (gr > M - 1) gr = M - 1;
      *(float4*)&As[r * 68 + kk] = *(const float4*)(A + (size_t)gr * 64 + kk);
    }
    __syncthreads();
    #pragma unroll 8
    for (int k = 0; k < 64; ++k) {
      float4 wa = *(const float4*)&Ws[k * 128 + tx * 4];
      float4 wb = *(const float4*)&Ws[k * 128 + 64 + tx * 4];
      float a0 = As[(ty * 4 + 0) * 68 + k];
      float a1 = As[(ty * 4 + 1) * 68 + k];
      float a2 = As[(ty * 4 + 2) * 68 + k];
      float a3 = As[(ty * 4 + 3) * 68 + k];
      accA[0][0] += a0 * wa.x; accA[0][1] += a0 * wa.y; accA[0][2] += a0 * wa.z; accA[0][3] += a0 * wa.w;
      accA[1][0] += a1 * wa.x; accA[1][1] += a1 * wa.y; accA[1][2] += a1 * wa.z; accA[1][3] += a1 * wa.w;
      accA[2][0] += a2 * wa.x; accA[2][1] += a2 * wa.y; accA[2][2] += a2 * wa.z; accA[2][3] += a2 * wa.w;
      accA[3][0] += a3 * wa.x; accA[3][1] += a3 * wa.y; accA[3][2] += a3 * wa.z; accA[3][3] += a3 * wa.w;
      accB[0][0] += a0 * wb.x; accB[0][1] += a0 * wb.y; accB[0][2] += a0 * wb.z; accB[0][3] += a0 * wb.w;
      accB[1][0] += a1 * wb.x; accB[1][1] += a1 * wb.y; accB[1][2] += a1 * wb.z; accB[1][3] += a1 * wb.w;
      accB[2][0] += a2 * wb.x; accB[2][1] += a2 * wb.y; accB[2][2] += a2 * wb.z; accB[2][3] += a2 * wb.w;
      accB[3][0] += a3 * wb.x; accB[3][1] += a3 * wb.y; accB[3][2] += a3 * wb.z; accB[3][3] += a3 * wb.w;
    }
    #pragma unroll
    for (int r = 0; r < 4; ++r) {
      int gr = row0 + ty * 4 + r;
      if (gr < M) {
        ushort4 g;
        g.x = f2bf(accA[r][0]); g.y = f2bf(accA[r][1]);
        g.z = f2bf(accA[r][2]); g.w = f2bf(accA[r][3]);
        *(ushort4*)(Ga + (size_t)gr * 64 + tx * 4) = g;
        *(float4*)(Tb + (size_t)gr * 64 + tx * 4) =
            make_float4(accB[r][0] + bvB.x, accB[r][1] + bvB.y,
                        accB[r][2] + bvB.z, accB[r][3] + bvB.w);
      }
    }
  }
}

// ---------------------------------------------------------------------------
// Fused aggregation x2 (proven body): out = relu(mean bf16 G[j,:] + T[n,:])
// ptr is int2{start,end} per node (buckets have padded capacity regions).
// ---------------------------------------------------------------------------
__global__ __launch_bounds__(256) void agg2(
    const unsigned short* __restrict__ G0, const float* T0,
    const int2* __restrict__ ptr0, const int* __restrict__ idx0, float* out0,
    const unsigned short* __restrict__ G1, const float* T1,
    const int2* __restrict__ ptr1, const int* __restrict__ idx1, float* out1,
    int n_dst)
{
  const int lane = threadIdx.x & 63;
  const int sub = lane >> 5;            // node within wave (0/1)
  const int s32 = lane & 31;
  const int k = s32 >> 4;               // edge parity slot (0/1)
  const int c4 = (s32 & 15) << 2;       // first of 4 channels this lane owns
  int wave = blockIdx.x * 4 + (threadIdx.x >> 6);
  const int nwh = (gridDim.x * 4) >> 1;
  const unsigned short* G; const float* T; const int2* ptr; const int* idx; float* out;
  if (wave < nwh) { G = G0; T = T0; ptr = ptr0; idx = idx0; out = out0; }
  else { G = G1; T = T1; ptr = ptr1; idx = idx1; out = out1; wave -= nwh; }

  for (int n0 = wave * 2; n0 < n_dst; n0 += nwh * 2) {
    const int n = n0 + sub;             // uniform across the 32-lane group
    if (n >= n_dst) continue;           // group-uniform branch
    const int2 pe = ptr[n];
    const int s = pe.x;
    const int e = pe.y;
    f32x4 t = {};
    if (k == 0)
      t = __builtin_nontemporal_load((const f32x4*)(T + (size_t)n * 64 + c4));
    float a0 = 0.f, a1 = 0.f, a2 = 0.f, a3 = 0.f;
    int i = s;
    // main: 16 edges per block; this lane covers edges i+2t+k, t=0..7
    for (; i + 16 <= e; i += 16) {
      int j0 = __builtin_nontemporal_load(idx + i + 0  + k);
      int j1 = __builtin_nontemporal_load(idx + i + 2  + k);
      int j2 = __builtin_nontemporal_load(idx + i + 4  + k);
      int j3 = __builtin_nontemporal_load(idx + i + 6  + k);
      int j4 = __builtin_nontemporal_load(idx + i + 8  + k);
      int j5 = __builtin_nontemporal_load(idx + i + 10 + k);
      int j6 = __builtin_nontemporal_load(idx + i + 12 + k);
      int j7 = __builtin_nontemporal_load(idx + i + 14 + k);
      uint2 g0 = *(const uint2*)(G + (size_t)j0 * 64 + c4);
      uint2 g1 = *(const uint2*)(G + (size_t)j1 * 64 + c4);
      uint2 g2 = *(const uint2*)(G + (size_t)j2 * 64 + c4);
      uint2 g3 = *(const uint2*)(G + (size_t)j3 * 64 + c4);
      uint2 g4 = *(const uint2*)(G + (size_t)j4 * 64 + c4);
      uint2 g5 = *(const uint2*)(G + (size_t)j5 * 64 + c4);
      uint2 g6 = *(const uint2*)(G + (size_t)j6 * 64 + c4);
      uint2 g7 = *(const uint2*)(G + (size_t)j7 * 64 + c4);
      a0 += bflo(g0.x); a1 += bfhi(g0.x); a2 += bflo(g0.y); a3 += bfhi(g0.y);
      a0 += bflo(g1.x); a1 += bfhi(g1.x); a2 += bflo(g1.y); a3 += bfhi(g1.y);
      a0 += bflo(g2.x); a1 += bfhi(g2.x); a2 += bflo(g2.y); a3 += bfhi(g2.y);
      a0 += bflo(g3.x); a1 += bfhi(g3.x); a2 += bflo(g3.y); a3 += bfhi(g3.y);
      a0 += bflo(g4.x); a1 += bfhi(g4.x); a2 += bflo(g4.y); a3 += bfhi(g4.y);
      a0 += bflo(g5.x); a1 += bfhi(g5.x); a2 += bflo(g5.y); a3 += bfhi(g5.y);
      a0 += bflo(g6.x); a1 += bfhi(g6.x); a2 += bflo(g6.y); a3 += bfhi(g6.y);
      a0 += bflo(g7.x); a1 += bfhi(g7.x); a2 += bflo(g7.y); a3 += bfhi(g7.y);
    }
    // tail: one predicated 16-edge block (fully pipelined, no serial chain)
    if (i < e) {
      const int em1 = e - 1;
      const int t0 = i + 0  + k, t1 = i + 2  + k, t2 = i + 4  + k, t3 = i + 6  + k;
      const int t4 = i + 8  + k, t5 = i + 10 + k, t6 = i + 12 + k, t7 = i + 14 + k;
      int j0 = __builtin_nontemporal_load(idx + min(t0, em1));
      int j1 = __builtin_nontemporal_load(idx + min(t1, em1));
      int j2 = __builtin_nontemporal_load(idx + min(t2, em1));
      int j3 = __builtin_nontemporal_load(idx + min(t3, em1));
      int j4 = __builtin_nontemporal_load(idx + min(t4, em1));
      int j5 = __builtin_nontemporal_load(idx + min(t5, em1));
      int j6 = __builtin_nontemporal_load(idx + min(t6, em1));
      int j7 = __builtin_nontemporal_load(idx + min(t7, em1));
      uint2 g0 = *(const uint2*)(G + (size_t)j0 * 64 + c4);
      uint2 g1 = *(const uint2*)(G + (size_t)j1 * 64 + c4);
      uint2 g2 = *(const uint2*)(G + (size_t)j2 * 64 + c4);
      uint2 g3 = *(const uint2*)(G + (size_t)j3 * 64 + c4);
      uint2 g4 = *(const uint2*)(G + (size_t)j4 * 64 + c4);
      uint2 g5 = *(const uint2*)(G + (size_t)j5 * 64 + c4);
      uint2 g6 = *(const uint2*)(G + (size_t)j6 * 64 + c4);
      uint2 g7 = *(const uint2*)(G + (size_t)j7 * 64 + c4);
      float w0 = (t0 <= em1) ? 1.f : 0.f;
      float w1 = (t1 <= em1) ? 1.f : 0.f;
      float w2 = (t2 <= em1) ? 1.f : 0.f;
      float w3 = (t3 <= em1) ? 1.f : 0.f;
      float w4 = (t4 <= em1) ? 1.f : 0.f;
      float w5 = (t5 <= em1) ? 1.f : 0.f;
      float w6 = (t6 <= em1) ? 1.f : 0.f;
      float w7 = (t7 <= em1) ? 1.f : 0.f;
      a0 = fmaf(bflo(g0.x), w0, a0); a1 = fmaf(bfhi(g0.x), w0, a1);
      a2 = fmaf(bflo(g0.y), w0, a2); a3 = fmaf(bfhi(g0.y), w0, a3);
      a0 = fmaf(bflo(g1.x), w1, a0); a1 = fmaf(bfhi(g1.x), w1, a1);
      a2 = fmaf(bflo(g1.y), w1, a2); a3 = fmaf(bfhi(g1.y), w1, a3);
      a0 = fmaf(bflo(g2.x), w2, a0); a1 = fmaf(bfhi(g2.x), w2, a1);
      a2 = fmaf(bflo(g2.y), w2, a2); a3 = fmaf(bfhi(g2.y), w2, a3);
      a0 = fmaf(bflo(g3.x), w3, a0); a1 = fmaf(bfhi(g3.x), w3, a1);
      a2 = fmaf(bflo(g3.y), w3, a2); a3 = fmaf(bfhi(g3.y), w3, a3);
      a0 = fmaf(bflo(g4.x), w4, a0); a1 = fmaf(bfhi(g4.x), w4, a1);
      a2 = fmaf(bflo(g4.y), w4, a2); a3 = fmaf(bfhi(g4.y), w4, a3);
      a0 = fmaf(bflo(g5.x), w5, a0); a1 = fmaf(bfhi(g5.x), w5, a1);
      a2 = fmaf(bflo(g5.y), w5, a2); a3 = fmaf(bfhi(g5.y), w5, a3);
      a0 = fmaf(bflo(g6.x), w6, a0); a1 = fmaf(bfhi(g6.x), w6, a1);
      a2 = fmaf(bflo(g6.y), w6, a2); a3 = fmaf(bfhi(g6.y), w6, a3);
      a0 = fmaf(bflo(g7.x), w7, a0); a1 = fmaf(bfhi(g7.x), w7, a1);
      a2 = fmaf(bflo(g7.y), w7, a2); a3 = fmaf(bfhi(g7.y), w7, a3);
    }
    // combine the two edge-parity partial sums (lane ^ 16 within each 32-group)
    a0 += __shfl_xor(a0, 16);
    a1 += __shfl_xor(a1, 16);
    a2 += __shfl_xor(a2, 16);
    a3 += __shfl_xor(a3, 16);
    const int deg = e - s;
    const float inv = 1.f / (float)(deg > 0 ? deg : 1);
    if (k == 0) {
      f32x4 o;
      o.x = fmaxf(fmaf(a0, inv, t.x), 0.f);
      o.y = fmaxf(fmaf(a1, inv, t.y), 0.f);
      o.z = fmaxf(fmaf(a2, inv, t.z), 0.f);
      o.w = fmaxf(fmaf(a3, inv, t.w), 0.f);
      __builtin_nontemporal_store(o, (f32x4*)(out + (size_t)n * 64 + c4));
    }
  }
}

// ---------------------------------------------------------------------------
// CSR build, 2 dispatches (fixed-capacity buckets, no hist/scan passes).
// K2: partition edges into bucket regions [b*BCAP, b*BCAP+cnt).
// ---------------------------------------------------------------------------
__global__ __launch_bounds__(256) void partition2(
    const int* __restrict__ srcA, const int* __restrict__ dstA, int* curA, unsigned int* pairsA,
    const int* __restrict__ srcB, const int* __restrict__ dstB, int* curB, unsigned int* pairsB,
    int E)
{
  __shared__ int h[NBKT];
  __shared__ int c[NBKT];
  const int half = gridDim.x >> 1;   // chunks per type
  const bool isB = (int)blockIdx.x >= half;
  const int chunk = isB ? blockIdx.x - half : blockIdx.x;
  const int* src = isB ? srcB : srcA;
  const int* dst = isB ? dstB : dstA;
  int* cur = isB ? curB : curA;
  unsigned int* pairs = isB ? pairsB : pairsA;
  const int e0 = chunk * ACHUNK;
  const int e1 = min(e0 + ACHUNK, E);
  for (int i = threadIdx.x; i < NBKT; i += 256) h[i] = 0;
  __syncthreads();
  for (int e = e0 + (int)threadIdx.x; e < e1; e += 256)
    atomicAdd(&h[__builtin_nontemporal_load(dst + e) >> 8], 1);
  __syncthreads();
  for (int i = threadIdx.x; i < NBKT; i += 256) {
    int v = h[i];
    if (v) c[i] = i * BCAP + atomicAdd(&cur[i], v);
  }
  __syncthreads();
  for (int e = e0 + (int)threadIdx.x; e < e1; e += 256) {
    int d = __builtin_nontemporal_load(dst + e);
    int s = __builtin_nontemporal_load(src + e);
    int b = d >> 8;
    int p = atomicAdd(&c[b], 1);
    pairs[p] = ((unsigned int)(d & 255) << 24) | (unsigned int)s;
  }
}

// K3: per-bucket CSR finalize: degree hist (LDS) -> scan -> int2 ptr write ->
// scatter src into the bucket's own idx region via LDS cursors.
__global__ __launch_bounds__(256) void bucket_fill(
    const unsigned int* __restrict__ pairsA, const int* __restrict__ cntA,
    int2* __restrict__ ptrA, int* __restrict__ idxA,
    const unsigned int* __restrict__ pairsB, const int* __restrict__ cntB,
    int2* __restrict__ ptrB, int* __restrict__ idxB, int n)
{
  __shared__ int h[NPB];
  __shared__ int cur[NPB];
  const bool isB = (int)blockIdx.x >= NBKT;
  const int b = isB ? blockIdx.x - NBKT : blockIdx.x;
  const unsigned int* pairs = isB ? pairsB : pairsA;
  const int* cnt = isB ? cntB : cntA;
  int2* ptr = isB ? ptrB : ptrA;
  int* idx = isB ? idxB : idxA;
  const int ebase = b * BCAP;
  const int eend = ebase + min(cnt[b], BCAP);
  const int t = threadIdx.x;
  h[t] = 0;
  __syncthreads();
  for (int e = ebase + t; e < eend; e += 256)
    atomicAdd(&h[pairs[e] >> 24], 1);
  __syncthreads();
  const int v = h[t];
  __syncthreads();
  for (int off = 1; off < 256; off <<= 1) {
    int x = 0;
    if (t >= off) x = h[t - off];
    __syncthreads();
    if (t >= off) h[t] += x;
    __syncthreads();
  }
  const int excl = h[t] - v;
  const int gnode = b * NPB + t;
  if (gnode < n) ptr[gnode] = make_int2(ebase + excl, ebase + excl + v);
  cur[t] = excl;
  __syncthreads();
  for (int e = ebase + t; e < eend; e += 256) {
    unsigned int pk = pairs[e];
    int p = atomicAdd(&cur[pk >> 24], 1);
    idx[ebase + p] = (int)(pk & 0xFFFFFFu);
  }
}

// ---------------------------------------------------------------------------
extern "C" void kernel_launch(void* const* d_in, const int* in_sizes, int n_in,
                              void* d_out, int out_size, void* d_ws, size_t ws_size,
                              hipStream_t stream) {
  const float* x_user = (const float*)d_in[0];
  const float* x_item = (const float*)d_in[1];
  const int*   edge_ui = (const int*)d_in[2];   // A: dst = item
  const int*   edge_iu = (const int*)d_in[3];   // B: dst = user
  const float* Wu = (const float*)d_in[4];
  const float* bu = (const float*)d_in[5];
  const float* Wi = (const float*)d_in[6];
  const float* bi = (const float*)d_in[7];
  const float* Wl = (const float*)d_in[8];
  const float* bl = (const float*)d_in[9];
  const float* Wr = (const float*)d_in[10];

  float* outU = (float*)d_out;
  float* outI = outU + (size_t)NUSER * HID;

  char* p = (char*)d_ws;
  auto alloc = [&](size_t bytes) -> void* {
    void* r = (void*)p; p += (bytes + 255) & ~(size_t)255; return r;
  };
  float* U = (float*)alloc((size_t)NUSER * HID * 4);          // hu0
  float* I = (float*)alloc((size_t)NITEM * HID * 4);          // hi0
  unsigned short* GA = (unsigned short*)alloc((size_t)NUSER * HID * 2);
  unsigned short* GB = (unsigned short*)alloc((size_t)NITEM * HID * 2);
  // pairs buffers alias GA/GB (NBKT*BCAP*4 = 8.0MB <= 12.8MB each): dead
  // before the first gemm_dual2 writes GA/GB.
  unsigned int* pairsA = (unsigned int*)GA;
  unsigned int* pairsB = (unsigned int*)GB;
  // cur: ONE carve, memset zeroed exactly.
  int* curA = (int*)alloc((size_t)(2 * NBKT) * 4);
  int* curB = curA + NBKT;
  int2* ptr_ui = (int2*)alloc(((size_t)NITEM) * 8);
  int2* ptr_iu = (int2*)alloc(((size_t)NUSER) * 8);
  int* idx_ui = (int*)alloc((size_t)NBKT * BCAP * 4);
  int* idx_iu = (int*)alloc((size_t)NBKT * BCAP * 4);

  // ---- CSR build: memset + 2 dispatches ----
  hipError_t _e = hipMemsetAsync(curA, 0, (size_t)(2 * NBKT) * 4, stream); (void)_e;
  partition2<<<2 * NCHUNK, 256, 0, stream>>>(
      edge_ui, edge_ui + NEDGE, curA, pairsA,
      edge_iu, edge_iu + NEDGE, curB, pairsB, NEDGE);
  bucket_fill<<<2 * NBKT, 256, 0, stream>>>(pairsA, curA, ptr_ui, idx_ui,
                                            pairsB, curB, ptr_iu, idx_iu, NITEM);

  const int AGG_B = 2 * ((NUSER / 2 + 3) / 4); // 25000

  const float* Wl00 = Wl;             const float* Wl01 = Wl + 4096;
  const float* Wl10 = Wl + 2 * 4096;  const float* Wl11 = Wl + 3 * 4096;
  const float* Wr00 = Wr;             const float* Wr01 = Wr + 4096;
  const float* Wr10 = Wr + 2 * 4096;  const float* Wr11 = Wr + 3 * 4096;
  const float* bl00 = bl;             const float* bl01 = bl + 64;
  const float* bl10 = bl + 128;       const float* bl11 = bl + 192;

  // ---- input linears (one fused dispatch, parity split) ----
  gemm_in2<<<1152, 256, 0, stream>>>(x_user, Wu, bu, U,
                                     x_item, Wi, bi, I, NUSER);

  // ---- layer 0 ----
  gemm_dual2<<<1536, 256, 0, stream>>>(U, Wl00, Wr01, bl01, GA, outU,
                                       I, Wl01, Wr00, bl00, GB, outI,
                                       NUSER);
  agg2<<<AGG_B, 256, 0, stream>>>(GA, outI, ptr_ui, idx_ui, outI,
                                  GB, outU, ptr_iu, idx_iu, outU, NITEM);

  // ---- layer 1 ----
  gemm_dual2<<<1536, 256, 0, stream>>>(outI, Wl11, Wr10, bl10, GA, outI,
                                       outU, Wl10, Wr11, bl11, GB, outU,
                                       NITEM);
  agg2<<<AGG_B, 256, 0, stream>>>(GA, outU, ptr_iu, idx_iu, outU,
                                  GB, outI, ptr_ui, idx_ui, outI, NUSER);
}